// Round 8
// baseline (29.255 us; speedup 1.0000x reference)
//
#include <hip/hip_runtime.h>
#include <math.h>

#define B_SZ   2048
#define D_SZ   4096
#define TB     4             // batch rows per block
#define NDC    16            // d-chunks looped per block
#define DC     256           // d's per chunk (== blockDim)
#define NBG    (B_SZ / TB)   // 512 blocks

// ws layout:
//   effp4 : 6*D_SZ float4 = 393216 B   (planar float4; 24 power-basis coefs/d)
//   effb  : D_SZ float4   =  65536 B
#define WS_EFFP_BYTES  (6 * D_SZ * 16)
#define WS_EFFB_BYTES  (D_SZ * 16)

// ---------------------------------------------------------------------------
// Convert B-spline coefs to truncated-power basis:
//   S(u) = p0 + p1 u + p2 u^2 + p3 u^3 + sum_{m=1..4} d_m max(u-m,0)^3
__global__ __launch_bounds__(256) void precompute_pow(
    const float* __restrict__ coef, const float* __restrict__ sb,
    const float* __restrict__ ssp,  const float* __restrict__ mask,
    float4* __restrict__ effp4, float4* __restrict__ effb)
{
    int d = blockIdx.x * 256 + threadIdx.x;
    if (d >= D_SZ) return;
    float v[24];
    #pragma unroll
    for (int o = 0; o < 3; ++o) {
        float m = mask[d*3 + o];
        float s = ssp[d*3 + o] * m;
        float k[8];
        #pragma unroll
        for (int n = 0; n < 8; ++n) k[n] = coef[(d*3 + o)*8 + n] * s;
        float A3[5];                       // t^3 coef of cell c's local poly
        #pragma unroll
        for (int c = 0; c < 5; ++c)
            A3[c] = (k[c+3] - k[c] + 3.0f*(k[c+1] - k[c+2])) * (1.0f/6.0f);
        v[0*3+o] = (k[0] + 4.0f*k[1] + k[2]) * (1.0f/6.0f);
        v[1*3+o] = (k[2] - k[0]) * 0.5f;
        v[2*3+o] = (k[0] + k[2]) * 0.5f - k[1];
        v[3*3+o] = A3[0];
        v[4*3+o] = A3[1] - A3[0];
        v[5*3+o] = A3[2] - A3[1];
        v[6*3+o] = A3[3] - A3[2];
        v[7*3+o] = A3[4] - A3[3];
    }
    #pragma unroll
    for (int g = 0; g < 6; ++g)
        effp4[(size_t)g * D_SZ + d] =
            make_float4(v[4*g+0], v[4*g+1], v[4*g+2], v[4*g+3]);
    float m0 = mask[d*3+0], m1 = mask[d*3+1], m2 = mask[d*3+2];
    effb[d] = make_float4(sb[d*3+0]*m0, sb[d*3+1]*m1, sb[d*3+2]*m2, 0.0f);
}

// ---------------------------------------------------------------------------
// DPP full-wave sum: result lands in lane 63.
template<int CTRL, int RMASK>
__device__ __forceinline__ float dpp_add(float v) {
    int x = __builtin_amdgcn_update_dpp(0, __float_as_int(v), CTRL, RMASK, 0xF, true);
    return v + __int_as_float(x);
}
__device__ __forceinline__ float wave_sum63(float v) {
    v = dpp_add<0x111, 0xF>(v);   // row_shr:1
    v = dpp_add<0x112, 0xF>(v);   // row_shr:2
    v = dpp_add<0x114, 0xF>(v);   // row_shr:4
    v = dpp_add<0x118, 0xF>(v);   // row_shr:8
    v = dpp_add<0x142, 0xA>(v);   // row_bcast:15 -> rows 1,3
    v = dpp_add<0x143, 0xC>(v);   // row_bcast:31 -> rows 2,3
    return v;                     // lane 63 = total
}

// ---------------------------------------------------------------------------
// Single-output kernel: block owns 4 batch rows; loops all 16 d-chunks with
// coef registers reloaded per chunk; in-register accumulation over all of D;
// one cheap block reduction; writes out directly (no partial, no 3rd kernel).
__global__ __launch_bounds__(256) void kan_main(
    const float* __restrict__ x, const float4* __restrict__ effp4,
    const float4* __restrict__ effb, const float* __restrict__ grid,
    float* __restrict__ out)
{
    __shared__ float tl[TB*3 * 4];         // 192 B: [q*3+o][wave]

    const int tid = threadIdx.x;
    const int bg  = blockIdx.x;            // 0..NBG-1
    const int b0  = bg * TB;
    const int lane = tid & 63;
    const int wv   = tid >> 6;

    const float g3   = grid[3];                     // -1
    const float invh = 1.0f / (grid[4] - grid[3]);  // 2.5
    // knot-fold constants: r_m(X) = max(X*invh + c_m, 0), c_m = -g3*invh - m
    const float c0 = -g3 * invh;
    const float c1 = c0 - 1.0f, c2 = c0 - 2.0f, c3 = c0 - 3.0f, c4 = c0 - 4.0f;

    float acc[TB][3];
    #pragma unroll
    for (int q = 0; q < TB; ++q) { acc[q][0]=0.f; acc[q][1]=0.f; acc[q][2]=0.f; }

    for (int dc = 0; dc < NDC; ++dc) {
        const int d = dc * DC + tid;
        // coef registers (7 coalesced float4 loads, L2-hot)
        float4 P0 = effp4[0*D_SZ + d], P1 = effp4[1*D_SZ + d],
               P2 = effp4[2*D_SZ + d], P3 = effp4[3*D_SZ + d],
               P4 = effp4[4*D_SZ + d], P5 = effp4[5*D_SZ + d];
        const float cp[24] = {P0.x,P0.y,P0.z,P0.w, P1.x,P1.y,P1.z,P1.w,
                              P2.x,P2.y,P2.z,P2.w, P3.x,P3.y,P3.z,P3.w,
                              P4.x,P4.y,P4.z,P4.w, P5.x,P5.y,P5.z,P5.w};
        float4 eb = effb[d];
        const float ebv[3] = {eb.x, eb.y, eb.z};
        const float* xp = x + (size_t)b0 * D_SZ + d;
        float xv[TB];
        #pragma unroll
        for (int q = 0; q < TB; ++q) xv[q] = xp[(size_t)q * D_SZ];

        #pragma unroll
        for (int q = 0; q < TB; ++q) {
            float X  = xv[q];
            float u  = fmaf(X, invh, c0);            // in [0,5)
            float u2 = u*u, u3 = u2*u;
            float e   = __expf(-X);
            float sil = X * __builtin_amdgcn_rcpf(1.0f + e);
            float r1 = fmaxf(fmaf(X, invh, c1), 0.0f), r13 = r1*r1*r1;
            float r2 = fmaxf(fmaf(X, invh, c2), 0.0f), r23 = r2*r2*r2;
            float r3 = fmaxf(fmaf(X, invh, c3), 0.0f), r33 = r3*r3*r3;
            float r4 = fmaxf(fmaf(X, invh, c4), 0.0f), r43 = r4*r4*r4;
            #pragma unroll
            for (int o = 0; o < 3; ++o) {
                float a = fmaf(sil, ebv[o], cp[0*3+o]);
                a = fmaf(cp[1*3+o], u,   a);
                a = fmaf(cp[2*3+o], u2,  a);
                a = fmaf(cp[3*3+o], u3,  a);
                a = fmaf(cp[4*3+o], r13, a);
                a = fmaf(cp[5*3+o], r23, a);
                a = fmaf(cp[6*3+o], r33, a);
                a = fmaf(cp[7*3+o], r43, a);
                acc[q][o] += a;
            }
        }
    }

    // ---- one block reduction: 12 DPP wave sums + tiny LDS combine ----
    #pragma unroll
    for (int q = 0; q < TB; ++q)
        #pragma unroll
        for (int o = 0; o < 3; ++o) {
            float s = wave_sum63(acc[q][o]);
            if (lane == 63) tl[(q*3 + o)*4 + wv] = s;
        }
    __syncthreads();
    if (tid < TB*3) {
        const float4 v = *(const float4*)&tl[tid*4];
        out[(size_t)(b0 + tid/3)*3 + (tid%3)] = (v.x + v.y) + (v.z + v.w);
    }
}

// ---------------------------------------------------------------------------
// Fallback (no workspace): block per b, raw arrays. Slower but correct.
__global__ __launch_bounds__(256) void kan_fallback(
    const float* __restrict__ x, const float* __restrict__ grid,
    const float* __restrict__ coef, const float* __restrict__ sb,
    const float* __restrict__ ssp,  const float* __restrict__ mask,
    float* __restrict__ out)
{
    __shared__ float red[3][4];
    int b = blockIdx.x, tid = threadIdx.x;
    float g3 = grid[3], invh = 1.0f / (grid[4] - grid[3]);
    float acc[3] = {0.f, 0.f, 0.f};
    for (int i = 0; i < D_SZ / 256; ++i) {
        int d = i * 256 + tid;
        float xv = x[(size_t)b * D_SZ + d];
        float u  = (xv - g3) * invh;
        float cfl = floorf(u);
        cfl = fminf(fmaxf(cfl, 0.0f), 4.0f);
        int  cell = (int)cfl;
        float t  = u - cfl;
        float t2 = t * t, t3 = t2 * t;
        float omt = 1.0f - t;
        float w0 = omt*omt*omt * (1.0f/6.0f);
        float w1 = (3.0f*t3 - 6.0f*t2 + 4.0f) * (1.0f/6.0f);
        float w2 = (-3.0f*t3 + 3.0f*t2 + 3.0f*t + 1.0f) * (1.0f/6.0f);
        float w3 = t3 * (1.0f/6.0f);
        float sil = xv / (1.0f + __expf(-xv));
        #pragma unroll
        for (int o = 0; o < 3; ++o) {
            const float* cp = &coef[(d*3 + o) * 8 + cell];
            float s = w0*cp[0] + w1*cp[1] + w2*cp[2] + w3*cp[3];
            float m = mask[d*3 + o];
            acc[o] += s * ssp[d*3 + o] * m + sil * sb[d*3 + o] * m;
        }
    }
    int lane = tid & 63, wv = tid >> 6;
    #pragma unroll
    for (int o = 0; o < 3; ++o) {
        float v = acc[o];
        #pragma unroll
        for (int off = 32; off >= 1; off >>= 1) v += __shfl_down(v, off, 64);
        if (lane == 0) red[o][wv] = v;
    }
    __syncthreads();
    if (tid < 3) {
        float s = red[tid][0] + red[tid][1] + red[tid][2] + red[tid][3];
        out[b * 3 + tid] = s;
    }
}

// ---------------------------------------------------------------------------
extern "C" void kernel_launch(void* const* d_in, const int* in_sizes, int n_in,
                              void* d_out, int out_size, void* d_ws, size_t ws_size,
                              hipStream_t stream)
{
    const float* x    = (const float*)d_in[0];
    const float* grid = (const float*)d_in[4];
    const float* coef = (const float*)d_in[5];
    const float* sb   = (const float*)d_in[6];
    const float* ssp  = (const float*)d_in[7];
    const float* mask = (const float*)d_in[8];
    float* out = (float*)d_out;

    size_t need = (size_t)WS_EFFP_BYTES + WS_EFFB_BYTES;
    if (ws_size >= need) {
        float4* effp4 = (float4*)d_ws;
        float4* effb  = (float4*)((char*)d_ws + WS_EFFP_BYTES);
        precompute_pow<<<D_SZ/256, 256, 0, stream>>>(coef, sb, ssp, mask, effp4, effb);
        kan_main<<<NBG, 256, 0, stream>>>(x, effp4, effb, grid, out);
    } else {
        kan_fallback<<<B_SZ, 256, 0, stream>>>(x, grid, coef, sb, ssp, mask, out);
    }
}

// Round 9
// 26.017 us; speedup vs baseline: 1.1245x; 1.1245x over previous
//
#include <hip/hip_runtime.h>
#include <math.h>

#define B_SZ   2048
#define D_SZ   4096
#define TB     16            // batch rows per block (8 pairs)
#define NC     16            // d-chunks (256 d per block)
#define DC     256           // d's per block (== blockDim)
#define NBG    (B_SZ / TB)   // 128 batch groups

typedef float v2f __attribute__((ext_vector_type(2)));

// ws layout:
//   effs   : 7*D_SZ float4 = 458752 B   (planar float4; 27 basis coefs + pad)
//   partial: NC*B_SZ*3 f32 = 393216 B
#define WS_EFFS_BYTES  (7 * D_SZ * 16)
#define WS_PART_BYTES  (NC * B_SZ * 3 * 4)

// ---------------------------------------------------------------------------
// Basis set per (d,o): {1, u, u^2, u^3, r1^3, r2^3, r3^3, r4^3, silu(x)}
// where u=(x+1)*2.5 in [0,5), r_m = max(u-m,0).  Coef i = basis*3 + o,
// i=0..26 (27th slot padded), stored planar as 7 float4 per d.
__global__ __launch_bounds__(256) void precompute_pow(
    const float* __restrict__ coef, const float* __restrict__ sb,
    const float* __restrict__ ssp,  const float* __restrict__ mask,
    float4* __restrict__ effs)
{
    int d = blockIdx.x * 256 + threadIdx.x;
    if (d >= D_SZ) return;
    float vv[28];
    vv[27] = 0.0f;
    #pragma unroll
    for (int o = 0; o < 3; ++o) {
        float m = mask[d*3 + o];
        float s = ssp[d*3 + o] * m;
        float k[8];
        #pragma unroll
        for (int n = 0; n < 8; ++n) k[n] = coef[(d*3 + o)*8 + n] * s;
        float A3[5];                       // t^3 coef of cell c's local poly
        #pragma unroll
        for (int c = 0; c < 5; ++c)
            A3[c] = (k[c+3] - k[c] + 3.0f*(k[c+1] - k[c+2])) * (1.0f/6.0f);
        vv[0*3+o] = (k[0] + 4.0f*k[1] + k[2]) * (1.0f/6.0f);
        vv[1*3+o] = (k[2] - k[0]) * 0.5f;
        vv[2*3+o] = (k[0] + k[2]) * 0.5f - k[1];
        vv[3*3+o] = A3[0];
        vv[4*3+o] = A3[1] - A3[0];
        vv[5*3+o] = A3[2] - A3[1];
        vv[6*3+o] = A3[3] - A3[2];
        vv[7*3+o] = A3[4] - A3[3];
        vv[8*3+o] = sb[d*3 + o] * m;       // silu basis coef
    }
    #pragma unroll
    for (int p = 0; p < 7; ++p)
        effs[(size_t)p * D_SZ + d] =
            make_float4(vv[4*p+0], vv[4*p+1], vv[4*p+2], vv[4*p+3]);
}

// ---------------------------------------------------------------------------
// DPP 16-lane-group sum: lane 15 (mod 16) holds its row's total.
template<int CTRL>
__device__ __forceinline__ float dpp_add(float v) {
    int x = __builtin_amdgcn_update_dpp(0, __float_as_int(v), CTRL, 0xF, 0xF, true);
    return v + __int_as_float(x);
}
__device__ __forceinline__ float group16_sum(float v) {
    v = dpp_add<0x111>(v);   // row_shr:1
    v = dpp_add<0x112>(v);   // row_shr:2
    v = dpp_add<0x114>(v);   // row_shr:4
    v = dpp_add<0x118>(v);   // row_shr:8
    return v;
}

__device__ __forceinline__ v2f pk_fma(v2f a, v2f b, v2f c) {
    return __builtin_elementwise_fma(a, b, c);
}
__device__ __forceinline__ v2f splat(float s) { v2f v = {s, s}; return v; }

// ---------------------------------------------------------------------------
// Main kernel: packed-f32 math over batch-row pairs; 27-coef register dot;
// immediate DPP reduce; plain partial stores.
__global__ __launch_bounds__(256) void kan_main(
    const float* __restrict__ x, const float4* __restrict__ effs,
    const float* __restrict__ grid, float* __restrict__ partial)
{
    __shared__ float tl[TB * 16 * 3];      // 3 KB: [q][group][o]

    const int tid = threadIdx.x;
    const int bg  = blockIdx.x;            // 0..NBG-1
    const int dc  = blockIdx.y;            // 0..NC-1
    const int d   = dc * DC + tid;
    const int lane = tid & 63;

    // ---- issue x loads first ----
    const int b0 = bg * TB;
    const float* xp = x + (size_t)b0 * D_SZ + d;
    float xv[TB];
    #pragma unroll
    for (int q = 0; q < TB; ++q) xv[q] = xp[(size_t)q * D_SZ];

    // ---- 27 basis coefs in registers (7 coalesced float4 loads) ----
    float4 P[7];
    #pragma unroll
    for (int p = 0; p < 7; ++p) P[p] = effs[(size_t)p * D_SZ + d];
    const float* cps = (const float*)P;    // static indexing only (unrolled)

    const float g3   = grid[3];                     // -1
    const float invh = 1.0f / (grid[4] - grid[3]);  // 2.5
    const v2f invh2 = splat(invh);
    const v2f c0v   = splat(-g3 * invh);

    #pragma unroll
    for (int pr = 0; pr < TB/2; ++pr) {
        v2f X = {xv[2*pr], xv[2*pr + 1]};
        v2f u  = pk_fma(X, invh2, c0v);             // in [0,5)
        v2f u2 = u * u, u3 = u2 * u;
        v2f r1 = __builtin_elementwise_max(u - splat(1.0f), splat(0.0f));
        v2f r2 = __builtin_elementwise_max(u - splat(2.0f), splat(0.0f));
        v2f r3 = __builtin_elementwise_max(u - splat(3.0f), splat(0.0f));
        v2f r4 = __builtin_elementwise_max(u - splat(4.0f), splat(0.0f));
        v2f r13 = (r1*r1)*r1, r23 = (r2*r2)*r2, r33 = (r3*r3)*r3, r43 = (r4*r4)*r4;
        float e0 = __expf(-X.x), e1 = __expf(-X.y);
        v2f sil = {X.x * __builtin_amdgcn_rcpf(1.0f + e0),
                   X.y * __builtin_amdgcn_rcpf(1.0f + e1)};

        #pragma unroll
        for (int o = 0; o < 3; ++o) {
            v2f a;
            a = pk_fma(u,   splat(cps[1*3+o]), splat(cps[0*3+o]));
            a = pk_fma(u2,  splat(cps[2*3+o]), a);
            a = pk_fma(u3,  splat(cps[3*3+o]), a);
            a = pk_fma(r13, splat(cps[4*3+o]), a);
            a = pk_fma(r23, splat(cps[5*3+o]), a);
            a = pk_fma(r33, splat(cps[6*3+o]), a);
            a = pk_fma(r43, splat(cps[7*3+o]), a);
            a = pk_fma(sil, splat(cps[8*3+o]), a);
            float s0 = group16_sum(a.x);
            float s1 = group16_sum(a.y);
            if ((lane & 15) == 15) {
                int g = tid >> 4;          // 0..15 unique per writer
                tl[((2*pr    )*16 + g)*3 + o] = s0;
                tl[((2*pr + 1)*16 + g)*3 + o] = s1;
            }
        }
    }

    __syncthreads();
    if (tid < TB*3) {
        int q = tid / 3, o = tid % 3;
        float s = 0.0f;
        #pragma unroll
        for (int g = 0; g < 16; ++g) s += tl[(q*16 + g)*3 + o];
        partial[((size_t)dc * B_SZ + (b0 + q))*3 + o] = s;
    }
}

// ---------------------------------------------------------------------------
__global__ __launch_bounds__(256) void reduce_partials(
    const float* __restrict__ partial, float* __restrict__ out)
{
    int i = blockIdx.x * 256 + threadIdx.x;
    if (i >= B_SZ * 3) return;
    float s = 0.0f;
    #pragma unroll
    for (int c = 0; c < NC; ++c) s += partial[(size_t)c * B_SZ * 3 + i];
    out[i] = s;
}

// ---------------------------------------------------------------------------
// Fallback (no workspace): block per b, raw arrays. Slower but correct.
__global__ __launch_bounds__(256) void kan_fallback(
    const float* __restrict__ x, const float* __restrict__ grid,
    const float* __restrict__ coef, const float* __restrict__ sb,
    const float* __restrict__ ssp,  const float* __restrict__ mask,
    float* __restrict__ out)
{
    __shared__ float red[3][4];
    int b = blockIdx.x, tid = threadIdx.x;
    float g3 = grid[3], invh = 1.0f / (grid[4] - grid[3]);
    float acc[3] = {0.f, 0.f, 0.f};
    for (int i = 0; i < D_SZ / 256; ++i) {
        int d = i * 256 + tid;
        float xv = x[(size_t)b * D_SZ + d];
        float u  = (xv - g3) * invh;
        float cfl = floorf(u);
        cfl = fminf(fmaxf(cfl, 0.0f), 4.0f);
        int  cell = (int)cfl;
        float t  = u - cfl;
        float t2 = t * t, t3 = t2 * t;
        float omt = 1.0f - t;
        float w0 = omt*omt*omt * (1.0f/6.0f);
        float w1 = (3.0f*t3 - 6.0f*t2 + 4.0f) * (1.0f/6.0f);
        float w2 = (-3.0f*t3 + 3.0f*t2 + 3.0f*t + 1.0f) * (1.0f/6.0f);
        float w3 = t3 * (1.0f/6.0f);
        float sil = xv / (1.0f + __expf(-xv));
        #pragma unroll
        for (int o = 0; o < 3; ++o) {
            const float* cp = &coef[(d*3 + o) * 8 + cell];
            float s = w0*cp[0] + w1*cp[1] + w2*cp[2] + w3*cp[3];
            float m = mask[d*3 + o];
            acc[o] += s * ssp[d*3 + o] * m + sil * sb[d*3 + o] * m;
        }
    }
    int lane = tid & 63, wv = tid >> 6;
    #pragma unroll
    for (int o = 0; o < 3; ++o) {
        float v = acc[o];
        #pragma unroll
        for (int off = 32; off >= 1; off >>= 1) v += __shfl_down(v, off, 64);
        if (lane == 0) red[o][wv] = v;
    }
    __syncthreads();
    if (tid < 3) {
        float s = red[tid][0] + red[tid][1] + red[tid][2] + red[tid][3];
        out[b * 3 + tid] = s;
    }
}

// ---------------------------------------------------------------------------
extern "C" void kernel_launch(void* const* d_in, const int* in_sizes, int n_in,
                              void* d_out, int out_size, void* d_ws, size_t ws_size,
                              hipStream_t stream)
{
    const float* x    = (const float*)d_in[0];
    const float* grid = (const float*)d_in[4];
    const float* coef = (const float*)d_in[5];
    const float* sb   = (const float*)d_in[6];
    const float* ssp  = (const float*)d_in[7];
    const float* mask = (const float*)d_in[8];
    float* out = (float*)d_out;

    size_t need = (size_t)WS_EFFS_BYTES + WS_PART_BYTES;
    if (ws_size >= need) {
        float4* effs    = (float4*)d_ws;
        float*  partial = (float*)((char*)d_ws + WS_EFFS_BYTES);
        precompute_pow<<<D_SZ/256, 256, 0, stream>>>(coef, sb, ssp, mask, effs);
        dim3 g(NBG, NC);
        kan_main<<<g, 256, 0, stream>>>(x, effs, grid, partial);
        reduce_partials<<<(B_SZ*3 + 255)/256, 256, 0, stream>>>(partial, out);
    } else {
        kan_fallback<<<B_SZ, 256, 0, stream>>>(x, grid, coef, sb, ssp, mask, out);
    }
}